// Round 4
// baseline (4999.545 us; speedup 1.0000x reference)
//
#include <hip/hip_runtime.h>
#include <math.h>

// ---------------------------------------------------------------------------
// HGT transformer layer, fp32 baseline.
// N=50000 nodes, D=128, H=8 heads, DH=16, E=300000 per edge type.
// ---------------------------------------------------------------------------

__device__ __forceinline__ float gelu_exact(float x) {
    return 0.5f * x * (1.0f + erff(x * 0.70710678118654752f));
}

__device__ __forceinline__ void atomicMaxFloat(float* addr, float val) {
    // monotone-encoding trick: works with init = -inf
    if (val >= 0.0f) atomicMax((int*)addr, __float_as_int(val));
    else             atomicMin((unsigned int*)addr, __float_as_uint(val));
}

// --------------------------- LayerNorm (rows of 128) -----------------------
__global__ __launch_bounds__(256) void ln_kernel(
    const float* __restrict__ x, const float* __restrict__ g,
    const float* __restrict__ b, float* __restrict__ out, int nrows)
{
    int row  = (int)((blockIdx.x * 256 + threadIdx.x) >> 6);
    int lane = threadIdx.x & 63;
    if (row >= nrows) return;
    float2 xv = *(const float2*)&x[(size_t)row * 128 + lane * 2];
    float s = xv.x + xv.y;
#pragma unroll
    for (int off = 32; off >= 1; off >>= 1) s += __shfl_xor(s, off, 64);
    float mu = s * (1.0f / 128.0f);
    float d0 = xv.x - mu, d1 = xv.y - mu;
    float v = d0 * d0 + d1 * d1;
#pragma unroll
    for (int off = 32; off >= 1; off >>= 1) v += __shfl_xor(v, off, 64);
    float rs = rsqrtf(v * (1.0f / 128.0f) + 1e-5f);
    float2 gv = *(const float2*)&g[lane * 2];
    float2 bv = *(const float2*)&b[lane * 2];
    float2 o;
    o.x = d0 * rs * gv.x + bv.x;
    o.y = d1 * rs * gv.y + bv.y;
    *(float2*)&out[(size_t)row * 128 + lane * 2] = o;
}

// --------------------------- fp32 tiled GEMM -------------------------------
// C[M,N] = A[M,K] @ B[K,N] (+bias) with fused epilogues:
//   EPI 0: C = acc + bias
//   EPI 1: C = gelu(acc + bias)
//   EPI 2: C = aux1 + s*(acc+bias) + (1-s)*aux2, s = sigmoid(*skipp)
//   EPI 3: C = aux1 + acc + bias
// BM=BN=64, BK=16, 256 threads, 4x4 per-thread tile. N,K multiples of 16.
template <int EPI>
__global__ __launch_bounds__(256) void gemm_f32(
    const float* __restrict__ A, const float* __restrict__ B,
    const float* __restrict__ bias, float* __restrict__ C,
    int M, int N, int K,
    const float* __restrict__ aux1, const float* __restrict__ aux2,
    const float* __restrict__ skipp)
{
    __shared__ __align__(16) float As[16][68];  // [k][m], pad 68 -> 2-way max
    __shared__ __align__(16) float Bs[16][64];  // [k][n]
    const int t  = threadIdx.x;
    const int bm = blockIdx.x * 64;
    const int bn = blockIdx.y * 64;
    const int ar = t >> 2, ak = (t & 3) << 2;   // A: row 0..63, k 0/4/8/12
    const int bk = t >> 4, bn4 = (t & 15) << 2; // B: k 0..15, n4 0..60
    const int tx = t & 15, ty = t >> 4;
    const int arow = bm + ar;
    float acc[4][4] = {};

    for (int k0 = 0; k0 < K; k0 += 16) {
        float4 av = make_float4(0.f, 0.f, 0.f, 0.f);
        if (arow < M) av = *(const float4*)&A[(size_t)arow * K + k0 + ak];
        As[ak + 0][ar] = av.x;
        As[ak + 1][ar] = av.y;
        As[ak + 2][ar] = av.z;
        As[ak + 3][ar] = av.w;
        *(float4*)&Bs[bk][bn4] = *(const float4*)&B[(size_t)(k0 + bk) * N + bn + bn4];
        __syncthreads();
#pragma unroll
        for (int kk = 0; kk < 16; ++kk) {
            float4 a = *(const float4*)&As[kk][ty << 2];
            float4 b = *(const float4*)&Bs[kk][tx << 2];
            acc[0][0] += a.x * b.x; acc[0][1] += a.x * b.y;
            acc[0][2] += a.x * b.z; acc[0][3] += a.x * b.w;
            acc[1][0] += a.y * b.x; acc[1][1] += a.y * b.y;
            acc[1][2] += a.y * b.z; acc[1][3] += a.y * b.w;
            acc[2][0] += a.z * b.x; acc[2][1] += a.z * b.y;
            acc[2][2] += a.z * b.z; acc[2][3] += a.z * b.w;
            acc[3][0] += a.w * b.x; acc[3][1] += a.w * b.y;
            acc[3][2] += a.w * b.z; acc[3][3] += a.w * b.w;
        }
        __syncthreads();
    }

    float s = 0.0f;
    if (EPI == 2) s = 1.0f / (1.0f + expf(-skipp[0]));
    float4 bb = *(const float4*)&bias[bn + (tx << 2)];
    const float bvals[4] = {bb.x, bb.y, bb.z, bb.w};

#pragma unroll
    for (int i = 0; i < 4; ++i) {
        int r = bm + (ty << 2) + i;
        if (r >= M) break;
        size_t cidx = (size_t)r * N + bn + (tx << 2);
        float o[4];
#pragma unroll
        for (int j = 0; j < 4; ++j) {
            float v = acc[i][j] + bvals[j];
            if (EPI == 1) v = gelu_exact(v);
            o[j] = v;
        }
        if (EPI == 2) {
            float4 a1 = *(const float4*)&aux1[cidx];
            float4 a2 = *(const float4*)&aux2[cidx];
            o[0] = a1.x + s * o[0] + (1.f - s) * a2.x;
            o[1] = a1.y + s * o[1] + (1.f - s) * a2.y;
            o[2] = a1.z + s * o[2] + (1.f - s) * a2.z;
            o[3] = a1.w + s * o[3] + (1.f - s) * a2.w;
        } else if (EPI == 3) {
            float4 a1 = *(const float4*)&aux1[cidx];
            o[0] += a1.x; o[1] += a1.y; o[2] += a1.z; o[3] += a1.w;
        }
        float4 ov = make_float4(o[0], o[1], o[2], o[3]);
        *(float4*)&C[cidx] = ov;
    }
}

// ------------------- per-node relation transforms --------------------------
// kA_t[n,h,f] = sum_d k[n,h,d] * a_t[h,d,f];  vM_t likewise with v, m_t.
// 2 nodes per block: t -> (node 0/1, head 0..7, f 0..15).
__global__ __launch_bounds__(256) void rel_transform(
    const float* __restrict__ kqv,
    const float* __restrict__ a_f, const float* __restrict__ m_f,
    const float* __restrict__ a_g, const float* __restrict__ m_g,
    float* __restrict__ kAf, float* __restrict__ kAg,
    float* __restrict__ vMf, float* __restrict__ vMg, int nnodes)
{
    __shared__ float sAf[8 * 16 * 17], sMf[8 * 16 * 17];
    __shared__ float sAg[8 * 16 * 17], sMg[8 * 16 * 17];
    for (int i = threadIdx.x; i < 2048; i += 256) {
        int o = (i >> 4) * 17 + (i & 15);  // pad stride 17 -> 2-way max
        sAf[o] = a_f[i]; sMf[o] = m_f[i];
        sAg[o] = a_g[i]; sMg[o] = m_g[i];
    }
    __syncthreads();
    int t = threadIdx.x;
    int f = t & 15, h = (t >> 4) & 7, nl = t >> 7;
    int n = blockIdx.x * 2 + nl;
    if (n >= nnodes) return;
    const float* kp = &kqv[(size_t)n * 384 + h * 16];
    const float* vp = kp + 256;
    float kd[16], vd[16];
#pragma unroll
    for (int i4 = 0; i4 < 4; ++i4) {
        float4 k4 = *(const float4*)&kp[i4 * 4];
        float4 v4 = *(const float4*)&vp[i4 * 4];
        kd[i4 * 4 + 0] = k4.x; kd[i4 * 4 + 1] = k4.y;
        kd[i4 * 4 + 2] = k4.z; kd[i4 * 4 + 3] = k4.w;
        vd[i4 * 4 + 0] = v4.x; vd[i4 * 4 + 1] = v4.y;
        vd[i4 * 4 + 2] = v4.z; vd[i4 * 4 + 3] = v4.w;
    }
    float rkf = 0.f, rkg = 0.f, rvf = 0.f, rvg = 0.f;
#pragma unroll
    for (int d = 0; d < 16; ++d) {
        int idx = (h * 16 + d) * 17 + f;
        rkf += kd[d] * sAf[idx];
        rkg += kd[d] * sAg[idx];
        rvf += vd[d] * sMf[idx];
        rvg += vd[d] * sMg[idx];
    }
    size_t o = (size_t)n * 128 + h * 16 + f;
    kAf[o] = rkf; kAg[o] = rkg; vMf[o] = rvf; vMg[o] = rvg;
}

// -------------------- init (ws is poisoned 0xAA every call) ----------------
__global__ __launch_bounds__(256) void init_seg(
    float* __restrict__ mx, float* __restrict__ denom,
    float* __restrict__ agg, int NH, int ND)
{
    int i = blockIdx.x * 256 + threadIdx.x;
    if (i < NH) {
        mx[i] = __int_as_float(0xff800000);  // -inf
        denom[i] = 0.0f;
    }
    if (i < ND) agg[i] = 0.0f;
}

// -------------------- pass A: logits + segment max -------------------------
__global__ __launch_bounds__(256) void edge_logits(
    const int* __restrict__ edge, const float* __restrict__ kqv,
    const float* __restrict__ kA, const float* __restrict__ p,
    float* __restrict__ logits, float* __restrict__ mx, int E, int rowoff)
{
    int gid = blockIdx.x * 256 + threadIdx.x;
    if (gid >= E * 8) return;
    int e = gid >> 3, h = gid & 7;
    int src = edge[e], dst = edge[E + e];
    const float* qp = &kqv[(size_t)dst * 384 + 128 + h * 16];
    const float* kp = &kA[(size_t)src * 128 + h * 16];
    float dot = 0.f;
#pragma unroll
    for (int i4 = 0; i4 < 4; ++i4) {
        float4 qv = *(const float4*)&qp[i4 * 4];
        float4 kv = *(const float4*)&kp[i4 * 4];
        dot += qv.x * kv.x + qv.y * kv.y + qv.z * kv.z + qv.w * kv.w;
    }
    float val = dot * p[h] * 0.25f;  // p/sqrt(16)
    logits[(size_t)(rowoff + e) * 8 + h] = val;
    atomicMaxFloat(&mx[dst * 8 + h], val);
}

// -------------------- pass B: exp + denom + weighted message sum -----------
__global__ __launch_bounds__(256) void edge_accum(
    const int* __restrict__ edge, const float* __restrict__ vM,
    const float* __restrict__ logits, const float* __restrict__ mx,
    float* __restrict__ denom, float* __restrict__ agg, int E, int rowoff)
{
    int gid = blockIdx.x * 256 + threadIdx.x;
    if (gid >= E * 8) return;
    int e = gid >> 3, h = gid & 7;
    int src = edge[e], dst = edge[E + e];
    float l = logits[(size_t)(rowoff + e) * 8 + h];
    float ev = expf(l - mx[dst * 8 + h]);
    atomicAdd(&denom[dst * 8 + h], ev);
    const float* vp = &vM[(size_t)src * 128 + h * 16];
    float* ap = &agg[(size_t)dst * 128 + h * 16];
#pragma unroll
    for (int i4 = 0; i4 < 4; ++i4) {
        float4 vv = *(const float4*)&vp[i4 * 4];
        atomicAdd(&ap[i4 * 4 + 0], ev * vv.x);
        atomicAdd(&ap[i4 * 4 + 1], ev * vv.y);
        atomicAdd(&ap[i4 * 4 + 2], ev * vv.z);
        atomicAdd(&ap[i4 * 4 + 3], ev * vv.w);
    }
}

// -------------------- normalize + gelu -------------------------------------
__global__ __launch_bounds__(256) void norm_gelu_kernel(
    const float* __restrict__ agg, const float* __restrict__ denom,
    float* __restrict__ out, int ND)
{
    int i = blockIdx.x * 256 + threadIdx.x;
    if (i >= ND) return;
    int n = i >> 7, h = (i >> 4) & 7;
    float a = agg[i] / (denom[n * 8 + h] + 1e-16f);
    out[i] = gelu_exact(a);
}

// ---------------------------------------------------------------------------
extern "C" void kernel_launch(void* const* d_in, const int* in_sizes, int n_in,
                              void* d_out, int out_size, void* d_ws, size_t ws_size,
                              hipStream_t stream)
{
    const float* x     = (const float*)d_in[0];
    const int*   ef    = (const int*)d_in[1];
    const int*   eg    = (const int*)d_in[2];
    const float* kqv_w = (const float*)d_in[3];
    const float* kqv_b = (const float*)d_in[4];
    const float* a_f   = (const float*)d_in[5];
    const float* m_f   = (const float*)d_in[6];
    const float* p_f   = (const float*)d_in[7];
    const float* a_g   = (const float*)d_in[8];
    const float* m_g   = (const float*)d_in[9];
    const float* p_g   = (const float*)d_in[10];
    const float* out_w = (const float*)d_in[11];
    const float* out_b = (const float*)d_in[12];
    const float* skip  = (const float*)d_in[13];
    const float* ln1_g = (const float*)d_in[14];
    const float* ln1_b = (const float*)d_in[15];
    const float* ln2_g = (const float*)d_in[16];
    const float* ln2_b = (const float*)d_in[17];
    const float* w1    = (const float*)d_in[18];
    const float* b1    = (const float*)d_in[19];
    const float* w2    = (const float*)d_in[20];
    const float* b2    = (const float*)d_in[21];
    float* out = (float*)d_out;

    const int D  = 128;
    const int Nn = in_sizes[0] / D;   // 50000
    const int E1 = in_sizes[1] / 2;   // 300000
    const int E2 = in_sizes[2] / 2;   // 300000
    const int Et = E1 + E2;

    // ---- workspace layout (floats). Total = 9*ND + 8*Et + 16*Nn ~= 63.2M.
    // Overlays: h1 reuses kAf..vMg (exactly 4*ND = N*512); gbuf reuses kqvb;
    // x1 reuses agg; xn2 reuses xn.
    float* ws = (float*)d_ws;
    size_t ND = (size_t)Nn * D;
    float* xn     = ws;                       // [ND]
    float* kqvb   = xn + ND;                  // [3*ND] k|q|v
    float* kAf    = kqvb + 3 * ND;            // [ND]
    float* kAg    = kAf + ND;                 // [ND]
    float* vMf    = kAg + ND;                 // [ND]
    float* vMg    = vMf + ND;                 // [ND]
    float* logits = vMg + ND;                 // [8*Et]
    float* mx     = logits + (size_t)Et * 8;  // [8*Nn]
    float* denom  = mx + (size_t)Nn * 8;      // [8*Nn]
    float* agg    = denom + (size_t)Nn * 8;   // [ND]
    float* h1   = kAf;   // overlay [N,512]
    float* gbuf = kqvb;  // overlay [ND]
    float* x1   = agg;   // overlay [ND]

    const int ln_grid = (Nn + 3) / 4;
    const int ndB     = (int)((ND + 255) / 256);

    // 1. xn = LN1(x)
    ln_kernel<<<ln_grid, 256, 0, stream>>>(x, ln1_g, ln1_b, xn, Nn);
    // 2. kqv = xn @ kqv_w + kqv_b
    {
        dim3 g((Nn + 63) / 64, 384 / 64);
        gemm_f32<0><<<g, 256, 0, stream>>>(xn, kqv_w, kqv_b, kqvb,
                                           Nn, 384, 128, nullptr, nullptr, nullptr);
    }
    // 3. per-node relation transforms
    rel_transform<<<(Nn + 1) / 2, 256, 0, stream>>>(
        kqvb, a_f, m_f, a_g, m_g, kAf, kAg, vMf, vMg, Nn);
    // 4. init segment buffers
    init_seg<<<ndB, 256, 0, stream>>>(mx, denom, agg, Nn * 8, (int)ND);
    // 5. logits + segment max (both edge types)
    edge_logits<<<(E1 * 8 + 255) / 256, 256, 0, stream>>>(
        ef, kqvb, kAf, p_f, logits, mx, E1, 0);
    edge_logits<<<(E2 * 8 + 255) / 256, 256, 0, stream>>>(
        eg, kqvb, kAg, p_g, logits, mx, E2, E1);
    // 6. exp + denom + weighted message aggregation
    edge_accum<<<(E1 * 8 + 255) / 256, 256, 0, stream>>>(
        ef, vMf, logits, mx, denom, agg, E1, 0);
    edge_accum<<<(E2 * 8 + 255) / 256, 256, 0, stream>>>(
        eg, vMg, logits, mx, denom, agg, E2, E1);
    // 7. gbuf = gelu(agg / (denom + 1e-16))
    norm_gelu_kernel<<<ndB, 256, 0, stream>>>(agg, denom, gbuf, (int)ND);
    // 8. x1 = x + sig*(gbuf @ out_w + out_b) + (1-sig)*xn
    {
        dim3 g((Nn + 63) / 64, 128 / 64);
        gemm_f32<2><<<g, 256, 0, stream>>>(gbuf, out_w, out_b, x1,
                                           Nn, 128, 128, x, xn, skip);
    }
    // 9. xn2 = LN2(x1)  (overwrites xn, which is dead now)
    ln_kernel<<<ln_grid, 256, 0, stream>>>(x1, ln2_g, ln2_b, xn, Nn);
    // 10. h1 = gelu(xn2 @ w1 + b1)
    {
        dim3 g((Nn + 63) / 64, 512 / 64);
        gemm_f32<1><<<g, 256, 0, stream>>>(xn, w1, b1, h1,
                                           Nn, 512, 128, nullptr, nullptr, nullptr);
    }
    // 11. out = x1 + h1 @ w2 + b2
    {
        dim3 g((Nn + 63) / 64, 128 / 64);
        gemm_f32<3><<<g, 256, 0, stream>>>(h1, w2, b2, out,
                                           Nn, 128, 512, x1, nullptr, nullptr);
    }
}

// Round 6
// 871.932 us; speedup vs baseline: 5.7339x; 5.7339x over previous
//
#include <hip/hip_runtime.h>
#include <math.h>

// ---------------------------------------------------------------------------
// HGT transformer layer. N=50000, D=128, H=8, DH=16, E=300000 per edge type.
// R5: replaced atomic segment-softmax (82M f32 atomics, 87% of runtime) with
// on-device CSR + fused per-destination online-softmax aggregation.
// ---------------------------------------------------------------------------

__device__ __forceinline__ float gelu_exact(float x) {
    return 0.5f * x * (1.0f + erff(x * 0.70710678118654752f));
}

// --------------------------- LayerNorm (rows of 128) -----------------------
__global__ __launch_bounds__(256) void ln_kernel(
    const float* __restrict__ x, const float* __restrict__ g,
    const float* __restrict__ b, float* __restrict__ out, int nrows)
{
    int row  = (int)((blockIdx.x * 256 + threadIdx.x) >> 6);
    int lane = threadIdx.x & 63;
    if (row >= nrows) return;
    float2 xv = *(const float2*)&x[(size_t)row * 128 + lane * 2];
    float s = xv.x + xv.y;
#pragma unroll
    for (int off = 32; off >= 1; off >>= 1) s += __shfl_xor(s, off, 64);
    float mu = s * (1.0f / 128.0f);
    float d0 = xv.x - mu, d1 = xv.y - mu;
    float v = d0 * d0 + d1 * d1;
#pragma unroll
    for (int off = 32; off >= 1; off >>= 1) v += __shfl_xor(v, off, 64);
    float rs = rsqrtf(v * (1.0f / 128.0f) + 1e-5f);
    float2 gv = *(const float2*)&g[lane * 2];
    float2 bv = *(const float2*)&b[lane * 2];
    float2 o;
    o.x = d0 * rs * gv.x + bv.x;
    o.y = d1 * rs * gv.y + bv.y;
    *(float2*)&out[(size_t)row * 128 + lane * 2] = o;
}

// --------------------------- fp32 tiled GEMM -------------------------------
// C[M,N] = A[M,K] @ B[K,N] (+bias), epilogues:
//   0: +bias   1: gelu(+bias)   2: aux1 + s*(acc+bias) + (1-s)*aux2   3: aux1+acc+bias
template <int EPI>
__global__ __launch_bounds__(256) void gemm_f32(
    const float* __restrict__ A, const float* __restrict__ B,
    const float* __restrict__ bias, float* __restrict__ C,
    int M, int N, int K,
    const float* __restrict__ aux1, const float* __restrict__ aux2,
    const float* __restrict__ skipp)
{
    __shared__ __align__(16) float As[16][68];
    __shared__ __align__(16) float Bs[16][64];
    const int t  = threadIdx.x;
    const int bm = blockIdx.x * 64;
    const int bn = blockIdx.y * 64;
    const int ar = t >> 2, ak = (t & 3) << 2;
    const int bk = t >> 4, bn4 = (t & 15) << 2;
    const int tx = t & 15, ty = t >> 4;
    const int arow = bm + ar;
    float acc[4][4] = {};

    for (int k0 = 0; k0 < K; k0 += 16) {
        float4 av = make_float4(0.f, 0.f, 0.f, 0.f);
        if (arow < M) av = *(const float4*)&A[(size_t)arow * K + k0 + ak];
        As[ak + 0][ar] = av.x;
        As[ak + 1][ar] = av.y;
        As[ak + 2][ar] = av.z;
        As[ak + 3][ar] = av.w;
        *(float4*)&Bs[bk][bn4] = *(const float4*)&B[(size_t)(k0 + bk) * N + bn + bn4];
        __syncthreads();
#pragma unroll
        for (int kk = 0; kk < 16; ++kk) {
            float4 a = *(const float4*)&As[kk][ty << 2];
            float4 b = *(const float4*)&Bs[kk][tx << 2];
            acc[0][0] += a.x * b.x; acc[0][1] += a.x * b.y;
            acc[0][2] += a.x * b.z; acc[0][3] += a.x * b.w;
            acc[1][0] += a.y * b.x; acc[1][1] += a.y * b.y;
            acc[1][2] += a.y * b.z; acc[1][3] += a.y * b.w;
            acc[2][0] += a.z * b.x; acc[2][1] += a.z * b.y;
            acc[2][2] += a.z * b.z; acc[2][3] += a.z * b.w;
            acc[3][0] += a.w * b.x; acc[3][1] += a.w * b.y;
            acc[3][2] += a.w * b.z; acc[3][3] += a.w * b.w;
        }
        __syncthreads();
    }

    float s = 0.0f;
    if (EPI == 2) s = 1.0f / (1.0f + expf(-skipp[0]));
    float4 bb = *(const float4*)&bias[bn + (tx << 2)];
    const float bvals[4] = {bb.x, bb.y, bb.z, bb.w};

#pragma unroll
    for (int i = 0; i < 4; ++i) {
        int r = bm + (ty << 2) + i;
        if (r >= M) break;
        size_t cidx = (size_t)r * N + bn + (tx << 2);
        float o[4];
#pragma unroll
        for (int j = 0; j < 4; ++j) {
            float v = acc[i][j] + bvals[j];
            if (EPI == 1) v = gelu_exact(v);
            o[j] = v;
        }
        if (EPI == 2) {
            float4 a1 = *(const float4*)&aux1[cidx];
            float4 a2 = *(const float4*)&aux2[cidx];
            o[0] = a1.x + s * o[0] + (1.f - s) * a2.x;
            o[1] = a1.y + s * o[1] + (1.f - s) * a2.y;
            o[2] = a1.z + s * o[2] + (1.f - s) * a2.z;
            o[3] = a1.w + s * o[3] + (1.f - s) * a2.w;
        } else if (EPI == 3) {
            float4 a1 = *(const float4*)&aux1[cidx];
            o[0] += a1.x; o[1] += a1.y; o[2] += a1.z; o[3] += a1.w;
        }
        float4 ov = make_float4(o[0], o[1], o[2], o[3]);
        *(float4*)&C[cidx] = ov;
    }
}

// ------------------- per-node relation transforms --------------------------
__global__ __launch_bounds__(256) void rel_transform(
    const float* __restrict__ kqv,
    const float* __restrict__ a_f, const float* __restrict__ m_f,
    const float* __restrict__ a_g, const float* __restrict__ m_g,
    float* __restrict__ kAf, float* __restrict__ kAg,
    float* __restrict__ vMf, float* __restrict__ vMg, int nnodes)
{
    __shared__ float sAf[8 * 16 * 17], sMf[8 * 16 * 17];
    __shared__ float sAg[8 * 16 * 17], sMg[8 * 16 * 17];
    for (int i = threadIdx.x; i < 2048; i += 256) {
        int o = (i >> 4) * 17 + (i & 15);
        sAf[o] = a_f[i]; sMf[o] = m_f[i];
        sAg[o] = a_g[i]; sMg[o] = m_g[i];
    }
    __syncthreads();
    int t = threadIdx.x;
    int f = t & 15, h = (t >> 4) & 7, nl = t >> 7;
    int n = blockIdx.x * 2 + nl;
    if (n >= nnodes) return;
    const float* kp = &kqv[(size_t)n * 384 + h * 16];
    const float* vp = kp + 256;
    float kd[16], vd[16];
#pragma unroll
    for (int i4 = 0; i4 < 4; ++i4) {
        float4 k4 = *(const float4*)&kp[i4 * 4];
        float4 v4 = *(const float4*)&vp[i4 * 4];
        kd[i4 * 4 + 0] = k4.x; kd[i4 * 4 + 1] = k4.y;
        kd[i4 * 4 + 2] = k4.z; kd[i4 * 4 + 3] = k4.w;
        vd[i4 * 4 + 0] = v4.x; vd[i4 * 4 + 1] = v4.y;
        vd[i4 * 4 + 2] = v4.z; vd[i4 * 4 + 3] = v4.w;
    }
    float rkf = 0.f, rkg = 0.f, rvf = 0.f, rvg = 0.f;
#pragma unroll
    for (int d = 0; d < 16; ++d) {
        int idx = (h * 16 + d) * 17 + f;
        rkf += kd[d] * sAf[idx];
        rkg += kd[d] * sAg[idx];
        rvf += vd[d] * sMf[idx];
        rvg += vd[d] * sMg[idx];
    }
    size_t o = (size_t)n * 128 + h * 16 + f;
    kAf[o] = rkf; kAg[o] = rkg; vMf[o] = rvf; vMg[o] = rvg;
}

// -------------------- CSR build ---------------------------------------------
__global__ __launch_bounds__(256) void zero_deg(int* __restrict__ deg, int n) {
    int i = blockIdx.x * 256 + threadIdx.x;
    if (i < n) deg[i] = 0;
}

__global__ __launch_bounds__(256) void count_deg(
    const int* __restrict__ edge, int E, int* __restrict__ deg)
{
    int e = blockIdx.x * 256 + threadIdx.x;
    if (e >= E) return;
    atomicAdd(&deg[edge[E + e]], 1);
}

// single-block 2-level exclusive scan: deg[n] -> rowptr[n+1], cursor[n]
__global__ __launch_bounds__(1024) void scan_kernel(
    const int* __restrict__ deg, int* __restrict__ rowptr,
    int* __restrict__ cursor, int n)
{
    const int tid = threadIdx.x;
    const int CH = (n + 1023) / 1024;
    int beg = tid * CH, end = min(beg + CH, n);
    int s = 0;
    for (int i = beg; i < end; ++i) s += deg[i];
    __shared__ int tmp[1024];
    tmp[tid] = s;
    __syncthreads();
    for (int off = 1; off < 1024; off <<= 1) {
        int t = (tid >= off) ? tmp[tid - off] : 0;
        __syncthreads();
        tmp[tid] += t;
        __syncthreads();
    }
    int run = tmp[tid] - s;  // exclusive prefix of this chunk
    for (int i = beg; i < end; ++i) {
        int d = deg[i];
        rowptr[i] = run;
        cursor[i] = run;
        run += d;
    }
    if (tid == 1023) rowptr[n] = run;  // last chunk ends at n -> total
}

__global__ __launch_bounds__(256) void fill_csr(
    const int* __restrict__ edge, int E, unsigned int typebit,
    int* __restrict__ cursor, unsigned int* __restrict__ col)
{
    int e = blockIdx.x * 256 + threadIdx.x;
    if (e >= E) return;
    int src = edge[e], dst = edge[E + e];
    int pos = atomicAdd(&cursor[dst], 1);
    col[pos] = (unsigned int)src | (typebit << 31);
}

// -------------------- fused gather + online softmax + gelu -----------------
// 16 lanes per (dst, head) task; tasks 8*dst..8*dst+7 are consecutive, so each
// wave (4 tasks) shares one dst -> uniform loop bounds, and the 64 lanes of a
// wave read a contiguous 256B span of kA/vM per edge (fully coalesced).
__global__ __launch_bounds__(256) void fused_agg(
    const int* __restrict__ rowptr, const unsigned int* __restrict__ col,
    const float* __restrict__ kqv,
    const float* __restrict__ kAf, const float* __restrict__ kAg,
    const float* __restrict__ vMf, const float* __restrict__ vMg,
    const float* __restrict__ p_f, const float* __restrict__ p_g,
    float* __restrict__ outg, int nnodes)
{
    int task = blockIdx.x * 16 + (threadIdx.x >> 4);
    int f    = threadIdx.x & 15;
    if (task >= nnodes * 8) return;
    int dst = task >> 3, h = task & 7;
    const int foff = h * 16 + f;
    float q  = kqv[(size_t)dst * 384 + 128 + foff];
    float pf = p_f[h] * 0.25f;   // p / sqrt(DH)
    float pg = p_g[h] * 0.25f;
    int i = rowptr[dst], end = rowptr[dst + 1];
    float m = -1e30f, s = 0.f, o = 0.f;
    for (; i < end; ++i) {
        unsigned int c = col[i];
        int src = (int)(c & 0x7fffffffu);
        bool tg = (c >> 31) != 0u;
        size_t boff = (size_t)src * 128 + foff;
        float kv = tg ? kAg[boff] : kAf[boff];
        float part = q * kv;
        part += __shfl_xor(part, 1, 16);
        part += __shfl_xor(part, 2, 16);
        part += __shfl_xor(part, 4, 16);
        part += __shfl_xor(part, 8, 16);
        float logit = part * (tg ? pg : pf);
        float mn    = fmaxf(m, logit);
        float scale = expf(m - mn);      // first edge: exp(-1e30-l) = 0
        float ev    = expf(logit - mn);
        float vv = tg ? vMg[boff] : vMf[boff];
        s = s * scale + ev;
        o = o * scale + ev * vv;
        m = mn;
    }
    float r = o / (s + 1e-16f);          // deg==0 -> 0, matches reference
    outg[(size_t)dst * 128 + foff] = gelu_exact(r);
}

// ---------------------------------------------------------------------------
extern "C" void kernel_launch(void* const* d_in, const int* in_sizes, int n_in,
                              void* d_out, int out_size, void* d_ws, size_t ws_size,
                              hipStream_t stream)
{
    const float* x     = (const float*)d_in[0];
    const int*   ef    = (const int*)d_in[1];
    const int*   eg    = (const int*)d_in[2];
    const float* kqv_w = (const float*)d_in[3];
    const float* kqv_b = (const float*)d_in[4];
    const float* a_f   = (const float*)d_in[5];
    const float* m_f   = (const float*)d_in[6];
    const float* p_f   = (const float*)d_in[7];
    const float* a_g   = (const float*)d_in[8];
    const float* m_g   = (const float*)d_in[9];
    const float* p_g   = (const float*)d_in[10];
    const float* out_w = (const float*)d_in[11];
    const float* out_b = (const float*)d_in[12];
    const float* skip  = (const float*)d_in[13];
    const float* ln1_g = (const float*)d_in[14];
    const float* ln1_b = (const float*)d_in[15];
    const float* ln2_g = (const float*)d_in[16];
    const float* ln2_b = (const float*)d_in[17];
    const float* w1    = (const float*)d_in[18];
    const float* b1    = (const float*)d_in[19];
    const float* w2    = (const float*)d_in[20];
    const float* b2    = (const float*)d_in[21];
    float* out = (float*)d_out;

    const int D  = 128;
    const int Nn = in_sizes[0] / D;   // 50000
    const int E1 = in_sizes[1] / 2;   // 300000
    const int E2 = in_sizes[2] / 2;   // 300000
    const int Et = E1 + E2;

    // ---- workspace layout: 9*ND floats + (3N+1+2E) ints ~= 233 MB.
    // Overlays: h1 reuses kAf..vMg (4*ND = N*512, dead after fused_agg);
    // x1 lives in d_out (final gemm reads aux1[c] then writes C[c], 1 writer).
    float* ws = (float*)d_ws;
    size_t ND = (size_t)Nn * D;
    float* xn   = ws;             // [ND]
    float* kqvb = xn + ND;        // [3*ND] k|q|v
    float* kAf  = kqvb + 3 * ND;  // [ND]
    float* kAg  = kAf + ND;       // [ND]
    float* vMf  = kAg + ND;       // [ND]
    float* vMg  = vMf + ND;       // [ND]
    float* gagg = vMg + ND;       // [ND] gelu(agg)
    int* ibase  = (int*)(gagg + ND);
    int* deg    = ibase;                    // [N]
    int* rowptr = deg + Nn;                 // [N+1]
    int* cursor = rowptr + Nn + 1;          // [N]
    unsigned int* col = (unsigned int*)(cursor + Nn);  // [2E]
    float* h1 = kAf;      // overlay [N,512]
    float* x1 = out;      // x1 staged in d_out

    const int ln_grid = (Nn + 3) / 4;

    // 1. xn = LN1(x)
    ln_kernel<<<ln_grid, 256, 0, stream>>>(x, ln1_g, ln1_b, xn, Nn);
    // 2. kqv = xn @ kqv_w + kqv_b
    {
        dim3 g((Nn + 63) / 64, 384 / 64);
        gemm_f32<0><<<g, 256, 0, stream>>>(xn, kqv_w, kqv_b, kqvb,
                                           Nn, 384, 128, nullptr, nullptr, nullptr);
    }
    // 3. per-node relation transforms
    rel_transform<<<(Nn + 1) / 2, 256, 0, stream>>>(
        kqvb, a_f, m_f, a_g, m_g, kAf, kAg, vMf, vMg, Nn);
    // 4. CSR build: degree count -> scan -> scatter
    zero_deg<<<(Nn + 255) / 256, 256, 0, stream>>>(deg, Nn);
    count_deg<<<(E1 + 255) / 256, 256, 0, stream>>>(ef, E1, deg);
    count_deg<<<(E2 + 255) / 256, 256, 0, stream>>>(eg, E2, deg);
    scan_kernel<<<1, 1024, 0, stream>>>(deg, rowptr, cursor, Nn);
    fill_csr<<<(E1 + 255) / 256, 256, 0, stream>>>(ef, E1, 0u, cursor, col);
    fill_csr<<<(E2 + 255) / 256, 256, 0, stream>>>(eg, E2, 1u, cursor, col);
    // 5. fused: logits + online segment softmax + weighted agg + gelu
    fused_agg<<<(Nn * 8) / 16, 256, 0, stream>>>(
        rowptr, col, kqvb, kAf, kAg, vMf, vMg, p_f, p_g, gagg, Nn);
    // 6. x1 = x + sig*(gagg @ out_w + out_b) + (1-sig)*xn   (into d_out)
    {
        dim3 g((Nn + 63) / 64, 128 / 64);
        gemm_f32<2><<<g, 256, 0, stream>>>(gagg, out_w, out_b, x1,
                                           Nn, 128, 128, x, xn, skip);
    }
    // 7. xn2 = LN2(x1)  (xn dead, reuse)
    ln_kernel<<<ln_grid, 256, 0, stream>>>(x1, ln2_g, ln2_b, xn, Nn);
    // 8. h1 = gelu(xn2 @ w1 + b1)   (h1 overlays kAf..vMg)
    {
        dim3 g((Nn + 63) / 64, 512 / 64);
        gemm_f32<1><<<g, 256, 0, stream>>>(xn, w1, b1, h1,
                                           Nn, 512, 128, nullptr, nullptr, nullptr);
    }
    // 9. out = x1 + h1 @ w2 + b2   (reads x1 from d_out, writes d_out)
    {
        dim3 g((Nn + 63) / 64, 128 / 64);
        gemm_f32<3><<<g, 256, 0, stream>>>(h1, w2, b2, out,
                                           Nn, 128, 512, x1, nullptr, nullptr);
    }
}